// Round 3
// baseline (162.701 us; speedup 1.0000x reference)
//
#include <hip/hip_runtime.h>
#include <hip/hip_bf16.h>

typedef __bf16 bf16x8 __attribute__((ext_vector_type(8)));
typedef __bf16 bf16x4 __attribute__((ext_vector_type(4)));
typedef float  f32x4  __attribute__((ext_vector_type(4)));

#define T_SEQ 2048
#define D_HEAD 64
#define BH_N 32
#define NT_TILES (T_SEQ / 64)        // 32
#define QT_N 16                      // 128 q-rows per block
#define IMG_BYTES 16384              // per-(bh,kt) tile image: 8KB K + 8KB V
#define SCALE_LOG2 0.18033688011112042f   // 0.125 * log2(e)

#define WS_IMG ((size_t)0)
#define WS_MB  ((size_t)16u << 20)

static __device__ __forceinline__ f32x4 mfma32(bf16x8 a, bf16x8 b, f32x4 c) {
    return __builtin_amdgcn_mfma_f32_16x16x32_bf16(a, b, c, 0, 0, 0);
}

static __device__ __forceinline__ float fast_exp2(float x) {
#if __has_builtin(__builtin_amdgcn_exp2f)
    return __builtin_amdgcn_exp2f(x);   // raw v_exp_f32; inputs bounded, no fixup needed
#else
    return exp2f(x);
#endif
}

// async global->LDS, 16B per lane. LDS dest is wave-uniform base + lane*16 (HW rule);
// the swizzle lives in the GLOBAL image layout, LDS stays linear.
static __device__ __forceinline__ void gload16(const void* g, void* l, int lane) {
#if __has_builtin(__builtin_amdgcn_global_load_lds)
    (void)lane;
    __builtin_amdgcn_global_load_lds(
        (const __attribute__((address_space(1))) void*)g,
        (__attribute__((address_space(3))) void*)l, 16, 0, 0);
#else
    *((f32x4*)l + lane) = *(const f32x4*)g;
#endif
}

// ---------------- prepass: build per-tile LDS images ----------------
// Image for (bh,kt), 16KB:
//   K half (8KB): row kr (key 0..63) x 128B; 16B chunk m = K[key][d-chunk m^(kr&7)]
//   V half (8KB): row r  (d   0..63) x 128B; 16B chunk m: u=m^(r&7), kh=u&1, g=u>>1,
//       bytes0-7 = V[32kh+4g+{0..3}][d=r], bytes8-15 = V[32kh+16+4g+{0..3}][d=r]

__global__ __launch_bounds__(256) void prep_kv(const float* __restrict__ k,
                                               const float* __restrict__ v,
                                               char* __restrict__ img) {
    __shared__ __bf16 t[64][72];
    const int bh = blockIdx.y, tt = blockIdx.x, tid = threadIdx.x;
    char* ob = img + ((size_t)bh * NT_TILES + tt) * IMG_BYTES;
    {
        const int kr = tid >> 2, qd = tid & 3, ke = kr & 7;
        const size_t base = ((size_t)bh * T_SEQ + tt * 64 + kr) * D_HEAD + qd * 16;
        const float4 a0 = *(const float4*)(k + base);
        const float4 a1 = *(const float4*)(k + base + 4);
        const float4 a2 = *(const float4*)(k + base + 8);
        const float4 a3 = *(const float4*)(k + base + 12);
        bf16x8 w0, w1;
        w0[0]=(__bf16)a0.x; w0[1]=(__bf16)a0.y; w0[2]=(__bf16)a0.z; w0[3]=(__bf16)a0.w;
        w0[4]=(__bf16)a1.x; w0[5]=(__bf16)a1.y; w0[6]=(__bf16)a1.z; w0[7]=(__bf16)a1.w;
        w1[0]=(__bf16)a2.x; w1[1]=(__bf16)a2.y; w1[2]=(__bf16)a2.z; w1[3]=(__bf16)a2.w;
        w1[4]=(__bf16)a3.x; w1[5]=(__bf16)a3.y; w1[6]=(__bf16)a3.z; w1[7]=(__bf16)a3.w;
        *(bf16x8*)(ob + kr * 128 + (((2 * qd + 0) ^ ke) << 4)) = w0;
        *(bf16x8*)(ob + kr * 128 + (((2 * qd + 1) ^ ke) << 4)) = w1;
    }
    {
        const int tr = tid >> 4, c4 = (tid & 15) * 4;
        const float* src = v + ((size_t)bh * T_SEQ + tt * 64) * D_HEAD;
#pragma unroll
        for (int p = 0; p < 4; ++p) {
            const int row = p * 16 + tr;
            const float4 f = *(const float4*)(src + row * D_HEAD + c4);
            t[c4+0][row] = (__bf16)f.x; t[c4+1][row] = (__bf16)f.y;
            t[c4+2][row] = (__bf16)f.z; t[c4+3][row] = (__bf16)f.w;
        }
        __syncthreads();
        const int d = tid >> 2;
        char* vb = ob + 8192 + d * 128;
#pragma unroll
        for (int mi = 0; mi < 2; ++mi) {
            const int m  = (tid & 3) * 2 + mi;
            const int u  = m ^ (d & 7);
            const int k0 = (u & 1) * 32 + (u >> 1) * 4;
            const bf16x4 lo = *(const bf16x4*)&t[d][k0];
            const bf16x4 hi = *(const bf16x4*)&t[d][k0 + 16];
            *(bf16x8*)(vb + m * 16) = __builtin_shufflevector(lo, hi, 0,1,2,3,4,5,6,7);
        }
    }
}

__global__ void mpack(const int* __restrict__ m, unsigned long long* __restrict__ mb) {
    const int i = blockIdx.x * 256 + threadIdx.x;
    const unsigned long long b = __ballot(m[i] != 0);
    if ((threadIdx.x & 63) == 0) mb[i >> 6] = b;
}

// ---------------- main kernel ----------------
// Block = 512 thr = 8 waves over 128 q-rows: wave -> (qp = w&3: which 32-q group,
// kh = w>>2: which 32-key half). QTILE=128 halves per-block image re-reads (512MB -> 256MB
// of cache traffic per launch); XCD-aware 1D-grid swizzle gives each XCD 4 bh x 16 qt
// co-resident blocks -> per-XCD working set (4 images + mask bits) ~2.5MB < 4MB L2, so
// tile prefetches hit the local L2 instead of LLC. Per-wave inner work is unchanged from
// attn9 (32q x 32k per iter, merged 16x16x32 PV/rowsum, image staging via global_load_lds).

__global__ __launch_bounds__(512, 4) void attn10(
    const float* __restrict__ q, const char* __restrict__ img,
    const unsigned long long* __restrict__ mb, float* __restrict__ out)
{
    // XCD swizzle: linear block id -> (bh, qt) s.t. XCD x hosts bh in [4x, 4x+4), all qt.
    const int l   = blockIdx.x;          // 0..511
    const int m_  = l >> 3;              // 0..63
    const int bh  = ((l & 7) << 2) | (m_ & 3);
    const int qt  = m_ >> 2;             // 0..15 (128 q rows each)

    const int tid = threadIdx.x, wave = tid >> 6, lane = tid & 63;
    const int g = lane >> 4, ln = lane & 15;
    const int qp = wave & 3, kh = wave >> 2;

    __shared__ __align__(16) char smem[33280];
    float* Ep = (float*)smem;                // epilogue overlay: [2][64][64] f32 per pass
    float* Os = (float*)(smem + 32768);      // row sums [2][64] per pass

    const int qw = qt * 128 + qp * 32;

    // ---- Q B-frags (log2-scaled): lane n=ln holds Q[qw+qs*16+ln][kc*32+g*8+j]
    bf16x8 qf[2][2];
#pragma unroll
    for (int qs = 0; qs < 2; ++qs) {
        const float* qpt = q + ((size_t)bh * T_SEQ + qw + qs * 16 + ln) * D_HEAD + g * 8;
#pragma unroll
        for (int kc = 0; kc < 2; ++kc) {
            const float4 f0 = *(const float4*)(qpt + kc * 32);
            const float4 f1 = *(const float4*)(qpt + kc * 32 + 4);
            qf[qs][kc][0]=(__bf16)(f0.x*SCALE_LOG2); qf[qs][kc][1]=(__bf16)(f0.y*SCALE_LOG2);
            qf[qs][kc][2]=(__bf16)(f0.z*SCALE_LOG2); qf[qs][kc][3]=(__bf16)(f0.w*SCALE_LOG2);
            qf[qs][kc][4]=(__bf16)(f1.x*SCALE_LOG2); qf[qs][kc][5]=(__bf16)(f1.y*SCALE_LOG2);
            qf[qs][kc][6]=(__bf16)(f1.z*SCALE_LOG2); qf[qs][kc][7]=(__bf16)(f1.w*SCALE_LOG2);
        }
    }

    f32x4 o[2][4];
#pragma unroll
    for (int qs = 0; qs < 2; ++qs)
#pragma unroll
        for (int mt = 0; mt < 4; ++mt) o[qs][mt] = (f32x4){0.f, 0.f, 0.f, 0.f};
    f32x4 osum[2] = { (f32x4){0.f,0.f,0.f,0.f}, (f32x4){0.f,0.f,0.f,0.f} };
    const bf16x8 ones8 = { (__bf16)1.0f, (__bf16)1.0f, (__bf16)1.0f, (__bf16)1.0f,
                           (__bf16)1.0f, (__bf16)1.0f, (__bf16)1.0f, (__bf16)1.0f };

    const char* ibase = img + (size_t)bh * (NT_TILES * (size_t)IMG_BYTES);
    const unsigned long long* mrow0 = mb + (size_t)(qw + ln) * 32;
    const unsigned long long* mrow1 = mb + (size_t)(qw + 16 + ln) * 32;

    // prologue: tile 0 -> buf0 (8 waves x 2KB each)
    {
        const char* src = ibase + wave * 2048 + lane * 16;
        char* dst = smem + wave * 2048;
#pragma unroll
        for (int i = 0; i < 2; ++i) gload16(src + i * 1024, dst + i * 1024, lane);
    }
    unsigned long long mw0 = mrow0[0], mw1 = mrow1[0];
    __syncthreads();

    for (int kt = 0; kt < NT_TILES; ++kt) {
        const int b = kt & 1;
        unsigned long long mn0 = 0, mn1 = 0;
        if (kt < NT_TILES - 1) {
            const char* src = ibase + (size_t)(kt + 1) * IMG_BYTES + wave * 2048 + lane * 16;
            char* dst = smem + (b ^ 1) * 16384 + wave * 2048;
#pragma unroll
            for (int i = 0; i < 2; ++i) gload16(src + i * 1024, dst + i * 1024, lane);
            mn0 = mrow0[kt + 1]; mn1 = mrow1[kt + 1];
        }

        const char* KB = smem + b * 16384;
        const char* VB = KB + 8192;

        // pre-inverted keep-bit words for this wave's 32-key half, pre-shifted by g*4
        const unsigned nbs0 = (~(unsigned)(mw0 >> (kh << 5))) >> (g * 4);
        const unsigned nbs1 = (~(unsigned)(mw1 >> (kh << 5))) >> (g * 4);

        // ---- S^T = K.Q^T; exp2 + mask -> merged P frags (key perm: j<4 -> grp0, j>=4 -> grp1)
        bf16x8 pa8[2];
#pragma unroll
        for (int ntl = 0; ntl < 2; ++ntl) {
            const int row = (2 * kh + ntl) * 16 + ln;
            const int rb = row * 128 + ((g ^ (ln & 7)) << 4);
            const bf16x8 a0 = *(const bf16x8*)(KB + rb);
            const bf16x8 a1 = *(const bf16x8*)(KB + (rb ^ 64));
#pragma unroll
            for (int qs = 0; qs < 2; ++qs) {
                f32x4 c = (f32x4){0.f, 0.f, 0.f, 0.f};
                c = mfma32(a0, qf[qs][0], c);
                c = mfma32(a1, qf[qs][1], c);
                const unsigned nbs = qs ? nbs1 : nbs0;
#pragma unroll
                for (int r = 0; r < 4; ++r) {
                    const float e = fast_exp2(c[r]);
                    const int keep = (int)(nbs << (31 - (ntl * 16 + r))) >> 31;
                    const float p = __builtin_bit_cast(float,
                        __builtin_bit_cast(unsigned, e) & (unsigned)keep);
                    pa8[qs][ntl * 4 + r] = (__bf16)p;
                }
            }
        }

        // ---- row-sum + PV, all 16x16x32 (B-frag vv covers both key groups per b128 read)
#pragma unroll
        for (int qs = 0; qs < 2; ++qs) osum[qs] = mfma32(pa8[qs], ones8, osum[qs]);
#pragma unroll
        for (int mt = 0; mt < 4; ++mt) {
            const bf16x8 vv = *(const bf16x8*)(VB + (mt * 16 + ln) * 128
                                + ((((g << 1) | kh) ^ (ln & 7)) << 4));
#pragma unroll
            for (int qs = 0; qs < 2; ++qs)
                o[qs][mt] = mfma32(pa8[qs], vv, o[qs][mt]);
        }

        __syncthreads();   // drains prefetch vmcnt; all waves done reading buf b
        mw0 = mn0; mw1 = mn1;
    }

    // ---- epilogue: two 64-row passes; kh halves combined through LDS
#pragma unroll
    for (int pass = 0; pass < 2; ++pass) {
        if ((qp >> 1) == pass) {
            const int qpl = qp & 1;
#pragma unroll
            for (int qs = 0; qs < 2; ++qs) {
#pragma unroll
                for (int mt = 0; mt < 4; ++mt)
#pragma unroll
                    for (int r = 0; r < 4; ++r)
                        Ep[(size_t)kh * 4096 + (qpl * 32 + qs * 16 + g * 4 + r) * 64 + mt * 16 + ln] = o[qs][mt][r];
                if (ln == 0) {
#pragma unroll
                    for (int r = 0; r < 4; ++r)
                        Os[kh * 64 + qpl * 32 + qs * 16 + g * 4 + r] = osum[qs][r];
                }
            }
        }
        __syncthreads();
        // cooperative, coalesced output: 64 rows x 64 d fp32 (512 threads -> 2 quads each)
#pragma unroll
        for (int p2 = 0; p2 < 2; ++p2) {
            const int idx = p2 * 512 + tid;
            const int row = idx >> 4, c4 = (idx & 15) * 4;
            const float sl = Os[row] + Os[64 + row];
            const float inv = (sl > 0.f) ? (1.f / sl) : 0.f;
            const float4 a  = *(const float4*)(Ep + row * 64 + c4);
            const float4 b4 = *(const float4*)(Ep + 4096 + row * 64 + c4);
            const float4 st = { (a.x + b4.x) * inv, (a.y + b4.y) * inv,
                                (a.z + b4.z) * inv, (a.w + b4.w) * inv };
            *(float4*)(out + ((size_t)bh * T_SEQ + qt * 128 + pass * 64 + row) * D_HEAD + c4) = st;
        }
        if (pass == 0) __syncthreads();   // Ep/Os reused by pass 1
    }
}

extern "C" void kernel_launch(void* const* d_in, const int* in_sizes, int n_in,
                              void* d_out, int out_size, void* d_ws, size_t ws_size,
                              hipStream_t stream) {
    const float* q    = (const float*)d_in[0];
    const float* k    = (const float*)d_in[1];
    const float* v    = (const float*)d_in[2];
    const int*   mask = (const int*)d_in[3];
    float*       out  = (float*)d_out;

    char* img = (char*)d_ws + WS_IMG;
    unsigned long long* mbw = (unsigned long long*)((char*)d_ws + WS_MB);

    prep_kv<<<dim3(NT_TILES, BH_N), 256, 0, stream>>>(k, v, img);
    mpack<<<(T_SEQ * T_SEQ) / 256, 256, 0, stream>>>(mask, mbw);
    attn10<<<dim3(QT_N * BH_N), 512, 0, stream>>>(q, img, mbw, out);
}

// Round 4
// 159.512 us; speedup vs baseline: 1.0200x; 1.0200x over previous
//
#include <hip/hip_runtime.h>
#include <hip/hip_bf16.h>

typedef __bf16 bf16x8 __attribute__((ext_vector_type(8)));
typedef __bf16 bf16x4 __attribute__((ext_vector_type(4)));
typedef float  f32x4  __attribute__((ext_vector_type(4)));

#define T_SEQ 2048
#define D_HEAD 64
#define BH_N 32
#define NT_TILES (T_SEQ / 64)        // 32
#define QT_N 16                      // 128 q-rows per block
#define IMG_BYTES 16384              // per-(bh,kt) tile image: 8KB K + 8KB V
#define SCALE_LOG2 0.18033688011112042f   // 0.125 * log2(e)

#define WS_IMG ((size_t)0)
#define WS_MB  ((size_t)16u << 20)

static __device__ __forceinline__ f32x4 mfma32(bf16x8 a, bf16x8 b, f32x4 c) {
    return __builtin_amdgcn_mfma_f32_16x16x32_bf16(a, b, c, 0, 0, 0);
}

static __device__ __forceinline__ float fast_exp2(float x) {
#if __has_builtin(__builtin_amdgcn_exp2f)
    return __builtin_amdgcn_exp2f(x);   // raw v_exp_f32; inputs bounded, no fixup needed
#else
    return exp2f(x);
#endif
}

// async global->LDS, 16B per lane. LDS dest is wave-uniform base + lane*16 (HW rule);
// the swizzle lives in the GLOBAL image layout, LDS stays linear.
static __device__ __forceinline__ void gload16(const void* g, void* l, int lane) {
#if __has_builtin(__builtin_amdgcn_global_load_lds)
    (void)lane;
    __builtin_amdgcn_global_load_lds(
        (const __attribute__((address_space(1))) void*)g,
        (__attribute__((address_space(3))) void*)l, 16, 0, 0);
#else
    *((f32x4*)l + lane) = *(const f32x4*)g;
#endif
}

// ---------------- prepass: build per-tile LDS images ----------------
// Image for (bh,kt), 16KB:
//   K half (8KB): row kr (key 0..63) x 128B; 16B chunk m = K[key][d-chunk m^(kr&7)]
//   V half (8KB): row r  (d   0..63) x 128B; 16B chunk m: u=m^(r&7), kh=u&1, g=u>>1,
//       bytes0-7 = V[32kh+4g+{0..3}][d=r], bytes8-15 = V[32kh+16+4g+{0..3}][d=r]

__global__ __launch_bounds__(256) void prep_kv(const float* __restrict__ k,
                                               const float* __restrict__ v,
                                               char* __restrict__ img) {
    __shared__ __bf16 t[64][72];
    const int bh = blockIdx.y, tt = blockIdx.x, tid = threadIdx.x;
    char* ob = img + ((size_t)bh * NT_TILES + tt) * IMG_BYTES;
    {
        const int kr = tid >> 2, qd = tid & 3, ke = kr & 7;
        const size_t base = ((size_t)bh * T_SEQ + tt * 64 + kr) * D_HEAD + qd * 16;
        const float4 a0 = *(const float4*)(k + base);
        const float4 a1 = *(const float4*)(k + base + 4);
        const float4 a2 = *(const float4*)(k + base + 8);
        const float4 a3 = *(const float4*)(k + base + 12);
        bf16x8 w0, w1;
        w0[0]=(__bf16)a0.x; w0[1]=(__bf16)a0.y; w0[2]=(__bf16)a0.z; w0[3]=(__bf16)a0.w;
        w0[4]=(__bf16)a1.x; w0[5]=(__bf16)a1.y; w0[6]=(__bf16)a1.z; w0[7]=(__bf16)a1.w;
        w1[0]=(__bf16)a2.x; w1[1]=(__bf16)a2.y; w1[2]=(__bf16)a2.z; w1[3]=(__bf16)a2.w;
        w1[4]=(__bf16)a3.x; w1[5]=(__bf16)a3.y; w1[6]=(__bf16)a3.z; w1[7]=(__bf16)a3.w;
        *(bf16x8*)(ob + kr * 128 + (((2 * qd + 0) ^ ke) << 4)) = w0;
        *(bf16x8*)(ob + kr * 128 + (((2 * qd + 1) ^ ke) << 4)) = w1;
    }
    {
        const int tr = tid >> 4, c4 = (tid & 15) * 4;
        const float* src = v + ((size_t)bh * T_SEQ + tt * 64) * D_HEAD;
#pragma unroll
        for (int p = 0; p < 4; ++p) {
            const int row = p * 16 + tr;
            const float4 f = *(const float4*)(src + row * D_HEAD + c4);
            t[c4+0][row] = (__bf16)f.x; t[c4+1][row] = (__bf16)f.y;
            t[c4+2][row] = (__bf16)f.z; t[c4+3][row] = (__bf16)f.w;
        }
        __syncthreads();
        const int d = tid >> 2;
        char* vb = ob + 8192 + d * 128;
#pragma unroll
        for (int mi = 0; mi < 2; ++mi) {
            const int m  = (tid & 3) * 2 + mi;
            const int u  = m ^ (d & 7);
            const int k0 = (u & 1) * 32 + (u >> 1) * 4;
            const bf16x4 lo = *(const bf16x4*)&t[d][k0];
            const bf16x4 hi = *(const bf16x4*)&t[d][k0 + 16];
            *(bf16x8*)(vb + m * 16) = __builtin_shufflevector(lo, hi, 0,1,2,3,4,5,6,7);
        }
    }
}

__global__ void mpack(const int* __restrict__ m, unsigned long long* __restrict__ mb) {
    const int i = blockIdx.x * 256 + threadIdx.x;
    const unsigned long long b = __ballot(m[i] != 0);
    if ((threadIdx.x & 63) == 0) mb[i >> 6] = b;
}

// ---------------- main kernel ----------------
// attn11 = attn10 with: (1) K-loop unrolled x2, statically-named double buffers -> all LDS
// read offsets / stage addresses are loop-invariant and hoisted (no per-iter address VALU);
// (2) ds_reads batched ahead of each MFMA cluster; (3) s_setprio(1) around MFMA clusters
// (T5). Geometry, image layout, mask math, epilogue identical to attn10 (verified).

__global__ __launch_bounds__(512, 4) void attn11(
    const float* __restrict__ q, const char* __restrict__ img,
    const unsigned long long* __restrict__ mb, float* __restrict__ out)
{
    // XCD swizzle: linear block id -> (bh, qt) s.t. XCD x hosts bh in [4x, 4x+4), all qt.
    const int l   = blockIdx.x;          // 0..511
    const int m_  = l >> 3;              // 0..63
    const int bh  = ((l & 7) << 2) | (m_ & 3);
    const int qt  = m_ >> 2;             // 0..15 (128 q rows each)

    const int tid = threadIdx.x, wave = tid >> 6, lane = tid & 63;
    const int g = lane >> 4, ln = lane & 15;
    const int qp = wave & 3, kh = wave >> 2;

    __shared__ __align__(16) char smem[33280];
    float* Ep = (float*)smem;                // epilogue overlay: [2][64][64] f32 per pass
    float* Os = (float*)(smem + 32768);      // row sums [2][64] per pass

    const int qw = qt * 128 + qp * 32;

    // ---- Q B-frags (log2-scaled): lane n=ln holds Q[qw+qs*16+ln][kc*32+g*8+j]
    bf16x8 qf[2][2];
#pragma unroll
    for (int qs = 0; qs < 2; ++qs) {
        const float* qpt = q + ((size_t)bh * T_SEQ + qw + qs * 16 + ln) * D_HEAD + g * 8;
#pragma unroll
        for (int kc = 0; kc < 2; ++kc) {
            const float4 f0 = *(const float4*)(qpt + kc * 32);
            const float4 f1 = *(const float4*)(qpt + kc * 32 + 4);
            qf[qs][kc][0]=(__bf16)(f0.x*SCALE_LOG2); qf[qs][kc][1]=(__bf16)(f0.y*SCALE_LOG2);
            qf[qs][kc][2]=(__bf16)(f0.z*SCALE_LOG2); qf[qs][kc][3]=(__bf16)(f0.w*SCALE_LOG2);
            qf[qs][kc][4]=(__bf16)(f1.x*SCALE_LOG2); qf[qs][kc][5]=(__bf16)(f1.y*SCALE_LOG2);
            qf[qs][kc][6]=(__bf16)(f1.z*SCALE_LOG2); qf[qs][kc][7]=(__bf16)(f1.w*SCALE_LOG2);
        }
    }

    f32x4 o[2][4];
#pragma unroll
    for (int qs = 0; qs < 2; ++qs)
#pragma unroll
        for (int mt = 0; mt < 4; ++mt) o[qs][mt] = (f32x4){0.f, 0.f, 0.f, 0.f};
    f32x4 osum[2] = { (f32x4){0.f,0.f,0.f,0.f}, (f32x4){0.f,0.f,0.f,0.f} };
    const bf16x8 ones8 = { (__bf16)1.0f, (__bf16)1.0f, (__bf16)1.0f, (__bf16)1.0f,
                           (__bf16)1.0f, (__bf16)1.0f, (__bf16)1.0f, (__bf16)1.0f };

    const char* ibase = img + (size_t)bh * (NT_TILES * (size_t)IMG_BYTES);
    const unsigned long long* mrow0 = mb + (size_t)(qw + ln) * 32;
    const unsigned long long* mrow1 = mb + (size_t)(qw + 16 + ln) * 32;

    // ---- loop-invariant LDS read offsets (hoisted once)
    int koffs[2][2];
#pragma unroll
    for (int ntl = 0; ntl < 2; ++ntl) {
        const int row = (2 * kh + ntl) * 16 + ln;
        const int rb = row * 128 + ((g ^ (ln & 7)) << 4);
        koffs[ntl][0] = rb; koffs[ntl][1] = rb ^ 64;
    }
    int voffs[4];
#pragma unroll
    for (int mt = 0; mt < 4; ++mt)
        voffs[mt] = (mt * 16 + ln) * 128 + ((((g << 1) | kh) ^ (ln & 7)) << 4);

    char* buf0 = smem;
    char* buf1 = smem + 16384;

    auto stage = [&](int tile, char* dstbase) {
        const char* src = ibase + (size_t)tile * IMG_BYTES + wave * 2048 + lane * 16;
        char* dst = dstbase + wave * 2048;
        gload16(src, dst, lane);
        gload16(src + 1024, dst + 1024, lane);
    };

    auto compute_tile = [&](const char* KB, const char* VB,
                            unsigned long long w0, unsigned long long w1) {
        // pre-inverted keep-bit words for this wave's 32-key half, pre-shifted by g*4
        const unsigned nbs0 = (~(unsigned)(w0 >> (kh << 5))) >> (g * 4);
        const unsigned nbs1 = (~(unsigned)(w1 >> (kh << 5))) >> (g * 4);

        // batch the 4 K b128 reads up front
        bf16x8 ka[2][2];
#pragma unroll
        for (int ntl = 0; ntl < 2; ++ntl) {
            ka[ntl][0] = *(const bf16x8*)(KB + koffs[ntl][0]);
            ka[ntl][1] = *(const bf16x8*)(KB + koffs[ntl][1]);
        }

        // ---- S^T = K.Q^T; exp2 + mask -> merged P frags (key perm: j<4 grp0, j>=4 grp1)
        bf16x8 pa8[2];
#pragma unroll
        for (int ntl = 0; ntl < 2; ++ntl) {
#pragma unroll
            for (int qs = 0; qs < 2; ++qs) {
                f32x4 c = (f32x4){0.f, 0.f, 0.f, 0.f};
                __builtin_amdgcn_s_setprio(1);
                c = mfma32(ka[ntl][0], qf[qs][0], c);
                c = mfma32(ka[ntl][1], qf[qs][1], c);
                __builtin_amdgcn_s_setprio(0);
                const unsigned nbs = qs ? nbs1 : nbs0;
#pragma unroll
                for (int r = 0; r < 4; ++r) {
                    const float e = fast_exp2(c[r]);
                    const int keep = (int)(nbs << (31 - (ntl * 16 + r))) >> 31;
                    const float p = __builtin_bit_cast(float,
                        __builtin_bit_cast(unsigned, e) & (unsigned)keep);
                    pa8[qs][ntl * 4 + r] = (__bf16)p;
                }
            }
        }

        // ---- row-sum + PV, batched V reads then pure-MFMA cluster under setprio
        bf16x8 vv[4];
#pragma unroll
        for (int mt = 0; mt < 4; ++mt) vv[mt] = *(const bf16x8*)(VB + voffs[mt]);
        __builtin_amdgcn_s_setprio(1);
#pragma unroll
        for (int qs = 0; qs < 2; ++qs) osum[qs] = mfma32(pa8[qs], ones8, osum[qs]);
#pragma unroll
        for (int mt = 0; mt < 4; ++mt)
#pragma unroll
            for (int qs = 0; qs < 2; ++qs)
                o[qs][mt] = mfma32(pa8[qs], vv[mt], o[qs][mt]);
        __builtin_amdgcn_s_setprio(0);
    };

    // prologue: tile 0 -> buf0 (8 waves x 2KB each)
    stage(0, buf0);
    unsigned long long mwA0 = mrow0[0], mwA1 = mrow1[0];
    __syncthreads();

#pragma unroll 1
    for (int i = 0; i < NT_TILES / 2; ++i) {
        const int t = 2 * i;
        // half A: consume buf0 (tile t), prefetch tile t+1 -> buf1
        stage(t + 1, buf1);
        const unsigned long long mwB0 = mrow0[t + 1], mwB1 = mrow1[t + 1];
        compute_tile(buf0, buf0 + 8192, mwA0, mwA1);
        __syncthreads();
        // half B: consume buf1 (tile t+1), prefetch tile t+2 -> buf0
        if (i < NT_TILES / 2 - 1) {
            stage(t + 2, buf0);
            mwA0 = mrow0[t + 2]; mwA1 = mrow1[t + 2];
        }
        compute_tile(buf1, buf1 + 8192, mwB0, mwB1);
        __syncthreads();
    }

    // ---- epilogue: two 64-row passes; kh halves combined through LDS
#pragma unroll
    for (int pass = 0; pass < 2; ++pass) {
        if ((qp >> 1) == pass) {
            const int qpl = qp & 1;
#pragma unroll
            for (int qs = 0; qs < 2; ++qs) {
#pragma unroll
                for (int mt = 0; mt < 4; ++mt)
#pragma unroll
                    for (int r = 0; r < 4; ++r)
                        Ep[(size_t)kh * 4096 + (qpl * 32 + qs * 16 + g * 4 + r) * 64 + mt * 16 + ln] = o[qs][mt][r];
                if (ln == 0) {
#pragma unroll
                    for (int r = 0; r < 4; ++r)
                        Os[kh * 64 + qpl * 32 + qs * 16 + g * 4 + r] = osum[qs][r];
                }
            }
        }
        __syncthreads();
        // cooperative, coalesced output: 64 rows x 64 d fp32 (512 threads -> 2 quads each)
#pragma unroll
        for (int p2 = 0; p2 < 2; ++p2) {
            const int idx = p2 * 512 + tid;
            const int row = idx >> 4, c4 = (idx & 15) * 4;
            const float sl = Os[row] + Os[64 + row];
            const float inv = (sl > 0.f) ? (1.f / sl) : 0.f;
            const float4 a  = *(const float4*)(Ep + row * 64 + c4);
            const float4 b4 = *(const float4*)(Ep + 4096 + row * 64 + c4);
            const float4 st = { (a.x + b4.x) * inv, (a.y + b4.y) * inv,
                                (a.z + b4.z) * inv, (a.w + b4.w) * inv };
            *(float4*)(out + ((size_t)bh * T_SEQ + qt * 128 + pass * 64 + row) * D_HEAD + c4) = st;
        }
        if (pass == 0) __syncthreads();   // Ep/Os reused by pass 1
    }
}

extern "C" void kernel_launch(void* const* d_in, const int* in_sizes, int n_in,
                              void* d_out, int out_size, void* d_ws, size_t ws_size,
                              hipStream_t stream) {
    const float* q    = (const float*)d_in[0];
    const float* k    = (const float*)d_in[1];
    const float* v    = (const float*)d_in[2];
    const int*   mask = (const int*)d_in[3];
    float*       out  = (float*)d_out;

    char* img = (char*)d_ws + WS_IMG;
    unsigned long long* mbw = (unsigned long long*)((char*)d_ws + WS_MB);

    prep_kv<<<dim3(NT_TILES, BH_N), 256, 0, stream>>>(k, v, img);
    mpack<<<(T_SEQ * T_SEQ) / 256, 256, 0, stream>>>(mask, mbw);
    attn11<<<dim3(QT_N * BH_N), 512, 0, stream>>>(q, img, mbw, out);
}